// Round 11
// baseline (137.837 us; speedup 1.0000x reference)
//
#include <hip/hip_runtime.h>
#include <math.h>

#define N_OBJ 16
#define P 4096                     // P1 == P2
#define BLOCK 256
#define EPSF 1e-12f

// ---- grid-NN geometry ------------------------------------------------------
#define G 96
#define GG (G * G)                 // 9216 bins
#define NGRID (2 * N_OBJ)          // 32 grids: (object, target-set)
#define LO (-6.0f)
#define CELL 0.125f                // 12/96, exact binary
#define INV_CELL 8.0f
#define BPT (GG / BLOCK)           // 36 bins per thread in the scan
#define QPB (BLOCK / 4)            // 64 queries per block (4 lanes/query)
#define QBLOCKS (2 * N_OBJ * P / QPB) // 2048 blocks -> 8/CU

// ---------------------------------------------------------------------------
// R11 = R10 with a DISCRIMINATING DURATION PROBE: 3 replays of k_query_p1
// (byte-identical prologue + phase-1 only + atomicAdd to a dummy ws slot,
// never read). Real k_build/k_query unchanged -> passed/absmax unchanged.
//   query_p1 + gap = (dur_R11 - 91.4) / 3
// Pre-committed readout:
//   dur ~  97-105 -> phases 2/3 (straggler tail) own the ~28 us
//   dur ~ 150-190 -> uniform/structural cost; phases 2/3 innocent
//   dur ~ 115-135 -> both, ~half each
// ---------------------------------------------------------------------------

__device__ __forceinline__ float wave_sum(float s) {
#pragma unroll
    for (int off = 32; off > 0; off >>= 1)
        s += __shfl_xor(s, off, 64);
    return s;
}

// ---------------------------------------------------------------------------
// Kernel 1: grid build (unchanged from R7 — verified exact, ~5 us).
// ---------------------------------------------------------------------------
__global__ __launch_bounds__(BLOCK) void k_build(const float* __restrict__ s1,
                                                 const float* __restrict__ s2,
                                                 float2* __restrict__ pts,
                                                 unsigned* __restrict__ binStart,
                                                 unsigned* __restrict__ maskws) {
    int gid = blockIdx.x;          // 0..31
    int n = gid >> 1, t = gid & 1;
    int tid = threadIdx.x;
    const float2* src = (const float2*)(t ? s1 : s2) + n * P;

    __shared__ unsigned cnt[GG];       // counts -> starts -> cursors (36 KB)
    __shared__ unsigned wtot[BLOCK / 64];
    __shared__ float wq[BLOCK / 64];

    for (int i = tid; i < GG; i += BLOCK) cnt[i] = 0u;
    __syncthreads();

    float2 p[16];
    int b[16];
    float msum = 0.0f;
#pragma unroll
    for (int k = 0; k < 16; k++) {
        float2 v = src[k * BLOCK + tid];
        p[k] = v;
        msum += v.x + v.y;
        int bx = (int)((v.x - LO) * INV_CELL);
        int by = (int)((v.y - LO) * INV_CELL);
        bx = min(max(bx, 0), G - 1);
        by = min(max(by, 0), G - 1);
        b[k] = by * G + bx;
        atomicAdd(&cnt[b[k]], 1u);
    }
    msum = wave_sum(msum);
    if ((tid & 63) == 0) wq[tid >> 6] = msum;
    __syncthreads();               // counts + wq complete
    if (t == 0 && tid == 0) {
        float total = (wq[0] + wq[1]) + (wq[2] + wq[3]);
        maskws[n] = (total >= 0.0f) ? 1u : 0u;
    }

    // serial exclusive scan over this thread's 36 contiguous bins
    unsigned run = 0;
    int base = tid * BPT;
    for (int i = 0; i < BPT; i++) {
        unsigned cv = cnt[base + i];
        cnt[base + i] = run;
        run += cv;
    }
    // wave-level inclusive scan of per-thread totals via shfl_up
    unsigned x = run;
#pragma unroll
    for (int off = 1; off < 64; off <<= 1) {
        unsigned v = __shfl_up(x, off, 64);
        if ((tid & 63) >= off) x += v;
    }
    if ((tid & 63) == 63) wtot[tid >> 6] = x;
    __syncthreads();
    unsigned wpre = 0;
    for (int w2 = 0; w2 < (tid >> 6); w2++) wpre += wtot[w2];
    unsigned offs = wpre + x - run;    // exclusive prefix for this thread
    for (int i = 0; i < BPT; i++) cnt[base + i] += offs;
    __syncthreads();

    unsigned* bs = binStart + (size_t)gid * (GG + 1);
    for (int i = tid; i < GG; i += BLOCK) bs[i] = cnt[i];
    if (tid == 0) bs[GG] = P;
    __syncthreads();               // bs written before cnt becomes cursors

    float2* dst = pts + (size_t)gid * P;
#pragma unroll
    for (int k = 0; k < 16; k++) {
        unsigned idx = atomicAdd(&cnt[b[k]], 1u);
        dst[idx] = p[k];
    }
}

// ---------------------------------------------------------------------------
// Shared query machinery (identical math to R10; absmax 0.0 expected).
// ---------------------------------------------------------------------------
#define DIST(v) fmaf(nqx, (v).x, fmaf(nqy, (v).y, fmaf((v).x, (v).x, (v).y * (v).y)))

__device__ __forceinline__ void walk_range8(const float2* __restrict__ tp,
                                            unsigned i, unsigned ee,
                                            float nqx, float nqy, float& m) {
    for (; i + 8 <= ee; i += 8) {
        float2 a0 = tp[i+0], a1 = tp[i+1], a2 = tp[i+2], a3 = tp[i+3];
        float2 a4 = tp[i+4], a5 = tp[i+5], a6 = tp[i+6], a7 = tp[i+7];
        float d0 = DIST(a0), d1 = DIST(a1), d2 = DIST(a2), d3 = DIST(a3);
        float d4 = DIST(a4), d5 = DIST(a5), d6 = DIST(a6), d7 = DIST(a7);
        float m0 = fminf(fminf(d0, d1), fminf(d2, d3));
        float m1 = fminf(fminf(d4, d5), fminf(d6, d7));
        m = fminf(m, fminf(m0, m1));
    }
    for (; i < ee; ++i) {
        float2 a0 = tp[i];
        m = fminf(m, DIST(a0));
    }
}

__device__ __forceinline__ void walk_strided4(const float2* __restrict__ tp,
                                              unsigned i, unsigned ee,
                                              float nqx, float nqy, float& m) {
    for (; i + 12 < ee; i += 16) {
        float2 a0 = tp[i], a1 = tp[i+4], a2 = tp[i+8], a3 = tp[i+12];
        float d0 = DIST(a0), d1 = DIST(a1), d2 = DIST(a2), d3 = DIST(a3);
        m = fminf(m, fminf(fminf(d0, d1), fminf(d2, d3)));
    }
    for (; i < ee; i += 4) {
        float2 a0 = tp[i];
        m = fminf(m, DIST(a0));
    }
}

template <int W>
__device__ __forceinline__ void phase_windowed(const float2* __restrict__ tp,
                                               const unsigned* __restrict__ bs,
                                               int bx, int by, int sub, float c,
                                               float nqx, float nqy, float& m) {
    const float mc = m + c;                    // quad-uniform (post-combine)
    const float sr = sqrtf(fmaxf(mc, 0.0f));   // inf while m = inf
    const int w = (int)fminf(fmaf(sr, INV_CELL, 2.0f), (float)W);
    const int xs = max(bx - w, 0), xe = min(bx + w, G - 1);
#pragma unroll
    for (int jj = 0; jj < (2 * W + 4) / 4; jj++) {
        int j = jj * 4 + sub;                  // this lane's row index
        if (j <= 2 * W) {
            int dy = j - W;
            int ady = (dy < 0) ? -dy : dy;
            float yb = (float)(ady - 1) * CELL;    // ady<=1 -> <=0 -> never culls
            int y = by + dy;
            if ((ady <= 1 || yb * yb <= mc) && 0 <= y && y < G) {
                unsigned ss = bs[y * G + xs];
                unsigned ee = bs[y * G + xe + 1];
                walk_range8(tp, ss, ee, nqx, nqy, m);
            }
        }
    }
}

// ---------------------------------------------------------------------------
// PROBE kernel: prologue + phase 1 ONLY, result to dummy ws slot (kept live
// via the atomic side effect; never read). Measures the uniform per-wave cost.
// ---------------------------------------------------------------------------
__global__ __launch_bounds__(BLOCK) void k_query_p1(const float2* __restrict__ pts,
                                                    const unsigned* __restrict__ binStart,
                                                    const unsigned* __restrict__ maskws,
                                                    float* __restrict__ dummy) {
    int bid = blockIdx.x;
    int tid = threadIdx.x;
    int sub = tid & 3;
    int qi  = bid * QPB + (tid >> 2);
    int pass = qi >> 16;
    int n    = (qi >> 12) & 15;
    int qoff = qi & 4095;
    __shared__ float wq[BLOCK / 64];

    if (maskws[n] == 0u) return;

    int g_tgt = n * 2 + pass;
    int g_src = n * 2 + (1 - pass);
    const float2* tp   = pts + (size_t)g_tgt * P;
    const unsigned* bs = binStart + (size_t)g_tgt * (GG + 1);

    float2 q = pts[(size_t)g_src * P + qoff];
    float c   = fmaf(q.x, q.x, q.y * q.y);
    float nqx = -2.0f * q.x, nqy = -2.0f * q.y;
    int bx = min(max((int)((q.x - LO) * INV_CELL), 0), G - 1);
    int by = min(max((int)((q.y - LO) * INV_CELL), 0), G - 1);

    float m = INFINITY;

    {   // phase 1 only (byte-identical to k_query's)
        int xs = max(bx - 1, 0), xe = min(bx + 1, G - 1);
        unsigned sA = 0u, eA = 0u, sB, eB, sC = 0u, eC = 0u;
        if (by - 1 >= 0)    { sA = bs[(by - 1) * G + xs]; eA = bs[(by - 1) * G + xe + 1]; }
                              sB = bs[ by      * G + xs]; eB = bs[ by      * G + xe + 1];
        if (by + 1 <= G - 1){ sC = bs[(by + 1) * G + xs]; eC = bs[(by + 1) * G + xe + 1]; }
        walk_strided4(tp, sA + sub, eA, nqx, nqy, m);
        walk_strided4(tp, sB + sub, eB, nqx, nqy, m);
        walk_strided4(tp, sC + sub, eC, nqx, nqy, m);
    }
    m = fminf(m, __shfl_xor(m, 1, 64));
    m = fminf(m, __shfl_xor(m, 2, 64));

    float dq = (sub == 0) ? fminf(m + c, 1e30f) : 0.0f; // finite even if m=inf
    dq = wave_sum(dq);
    if ((tid & 63) == 0) wq[tid >> 6] = dq;
    __syncthreads();
    if (tid == 0) {
        float sum = (wq[0] + wq[1]) + (wq[2] + wq[3]);
        atomicAdd(dummy, sum); // side effect keeps everything live; never read
    }
}

// ---------------------------------------------------------------------------
// Kernel 2: REAL k_query — byte-identical to R10.
// ---------------------------------------------------------------------------
__global__ __launch_bounds__(BLOCK) void k_query(const float2* __restrict__ pts,
                                                 const unsigned* __restrict__ binStart,
                                                 const unsigned* __restrict__ maskws,
                                                 float* __restrict__ out) {
    int bid = blockIdx.x;
    int tid = threadIdx.x;
    int sub = tid & 3;             // lane within quad
    int qi  = bid * QPB + (tid >> 2);
    int pass = qi >> 16;
    int n    = (qi >> 12) & 15;
    int qoff = qi & 4095;
    __shared__ float wq[BLOCK / 64];

    if (maskws[n] == 0u) return;   // masked object contributes 0 (uniform exit)

    int g_tgt = n * 2 + pass;      // pass0 -> t0 (s2 grid), pass1 -> t1 (s1)
    int g_src = n * 2 + (1 - pass);
    const float2* tp   = pts + (size_t)g_tgt * P;
    const unsigned* bs = binStart + (size_t)g_tgt * (GG + 1);

    float2 q = pts[(size_t)g_src * P + qoff]; // bin-sorted: wave = nearby queries
    float c   = fmaf(q.x, q.x, q.y * q.y);
    float nqx = -2.0f * q.x, nqy = -2.0f * q.y;
    int bx = min(max((int)((q.x - LO) * INV_CELL), 0), G - 1);
    int by = min(max((int)((q.y - LO) * INV_CELL), 0), G - 1);

    float m = INFINITY;            // min of (y2 - 2<q,y>); dist^2 = m + c

    // ---- phase 1: fused 3x3 window, quad-strided batched candidates --------
    {
        int xs = max(bx - 1, 0), xe = min(bx + 1, G - 1);
        unsigned sA = 0u, eA = 0u, sB, eB, sC = 0u, eC = 0u;
        if (by - 1 >= 0)    { sA = bs[(by - 1) * G + xs]; eA = bs[(by - 1) * G + xe + 1]; }
                              sB = bs[ by      * G + xs]; eB = bs[ by      * G + xe + 1];
        if (by + 1 <= G - 1){ sC = bs[(by + 1) * G + xs]; eC = bs[(by + 1) * G + xe + 1]; }
        walk_strided4(tp, sA + sub, eA, nqx, nqy, m);
        walk_strided4(tp, sB + sub, eB, nqx, nqy, m);
        walk_strided4(tp, sC + sub, eC, nqx, nqy, m);
    }
    m = fminf(m, __shfl_xor(m, 1, 64));
    m = fminf(m, __shfl_xor(m, 2, 64));

    if (CELL * CELL < m + c) {                 // phase 2: 9x9 cap, m-culled
        phase_windowed<4>(tp, bs, bx, by, sub, c, nqx, nqy, m);
        m = fminf(m, __shfl_xor(m, 1, 64));
        m = fminf(m, __shfl_xor(m, 2, 64));

        if ((4 * CELL) * (4 * CELL) < m + c) { // phase 3: 33x33 cap, m-culled
            phase_windowed<16>(tp, bs, bx, by, sub, c, nqx, nqy, m);
            m = fminf(m, __shfl_xor(m, 1, 64));
            m = fminf(m, __shfl_xor(m, 2, 64));

            if ((16 * CELL) * (16 * CELL) < m + c) { // backstop: full grid
                float mc = m + c;
                for (int y = sub; y < G; y += 4) {
                    int ady = (y > by) ? (y - by) : (by - y);
                    float yb = (float)(ady - 1) * CELL;
                    if (ady <= 1 || yb * yb <= mc) {
                        unsigned ss = bs[y * G];
                        unsigned ee = bs[y * G + G];
                        walk_range8(tp, ss, ee, nqx, nqy, m);
                    }
                }
                m = fminf(m, __shfl_xor(m, 1, 64));
                m = fminf(m, __shfl_xor(m, 2, 64));
            }
        }
    }

    // ---- finalize: one contribution per query (sub==0), block reduce -------
    float dq = (sub == 0) ? sqrtf(fmaxf(m + c, EPSF)) : 0.0f;
    dq = wave_sum(dq);
    if ((tid & 63) == 0) wq[tid >> 6] = dq;
    __syncthreads();
    if (tid == 0) {
        float sum = (wq[0] + wq[1]) + (wq[2] + wq[3]);
        // contribution: 0.5 * (partial row-sum / P) / N, onto poison base
        atomicAdd(out, sum * (0.5f / (float)P / (float)N_OBJ));
    }
}

extern "C" void kernel_launch(void* const* d_in, const int* in_sizes, int n_in,
                              void* d_out, int out_size, void* d_ws, size_t ws_size,
                              hipStream_t stream) {
    const float* s1 = (const float*)d_in[0]; // [16,4096,2] fp32
    const float* s2 = (const float*)d_in[1]; // [16,4096,2] fp32
    float* out = (float*)d_out;              // scalar fp32

    float2* pts        = (float2*)d_ws;                   // 32*4096 float2 = 1 MB
    unsigned* binStart = (unsigned*)(pts + NGRID * P);    // 32*(GG+1) u32
    unsigned* maskws   = binStart + NGRID * (GG + 1);     // 16 u32
    float* dummy       = (float*)(maskws + 16);           // probe sink, never read

    k_build<<<NGRID, BLOCK, 0, stream>>>(s1, s2, pts, binStart, maskws);
    // --- probe: 3x phase-1-only replicas (see header comment) ---------------
    k_query_p1<<<QBLOCKS, BLOCK, 0, stream>>>(pts, binStart, maskws, dummy);
    k_query_p1<<<QBLOCKS, BLOCK, 0, stream>>>(pts, binStart, maskws, dummy);
    k_query_p1<<<QBLOCKS, BLOCK, 0, stream>>>(pts, binStart, maskws, dummy);
    k_query<<<QBLOCKS, BLOCK, 0, stream>>>(pts, binStart, maskws, out);
}